// Round 1
// baseline (2374.855 us; speedup 1.0000x reference)
//
#include <hip/hip_runtime.h>
#include <hip/hip_bf16.h>

#define HC 256      // H*C == IN
#define DHID 1024
#define NEG 0.2f
#define LN_EPS 1e-5f

typedef unsigned short u16;
typedef unsigned int u32;

__device__ __forceinline__ float bf2f(u16 u) {
  union { u32 i; float f; } v; v.i = ((u32)u) << 16; return v.f;
}
__device__ __forceinline__ u16 f2bf(float f) {
  union { float f; u32 i; } v; v.f = f;
  u32 r = v.i + 0x7fffu + ((v.i >> 16) & 1u);
  return (u16)(r >> 16);
}

// ---------------- GEMM 1: out_bf16 = A(f32)[M,K] @ B(f32)[K,NB] + bias ----------------
__global__ __launch_bounds__(256) void gemm_xw_bf16(
    const float* __restrict__ A, const float* __restrict__ B,
    const float* __restrict__ bias, u16* __restrict__ out,
    int M, int K, int NB)
{
  __shared__ float As[16][64];
  __shared__ float Bs[16][64];
  const int tid = threadIdx.x;
  const int tx = tid & 15, ty = tid >> 4;
  const int rowBase = blockIdx.x * 64;
  const int colBase = blockIdx.y * 64;
  const int la_r = tid >> 2, la_k = (tid & 3) << 2;
  const int lb_k = tid >> 4, lb_c = (tid & 15) << 2;
  float acc[4][4] = {};
  for (int k0 = 0; k0 < K; k0 += 16) {
    int ar = rowBase + la_r;
    float4 av = make_float4(0.f, 0.f, 0.f, 0.f);
    if (ar < M) av = *(const float4*)&A[(size_t)ar * K + k0 + la_k];
    As[la_k + 0][la_r] = av.x; As[la_k + 1][la_r] = av.y;
    As[la_k + 2][la_r] = av.z; As[la_k + 3][la_r] = av.w;
    *(float4*)&Bs[lb_k][lb_c] = *(const float4*)&B[(size_t)(k0 + lb_k) * NB + colBase + lb_c];
    __syncthreads();
#pragma unroll
    for (int k = 0; k < 16; ++k) {
      float a_[4], b_[4];
      *(float4*)a_ = *(const float4*)&As[k][ty << 2];
      *(float4*)b_ = *(const float4*)&Bs[k][tx << 2];
#pragma unroll
      for (int i = 0; i < 4; ++i)
#pragma unroll
        for (int j = 0; j < 4; ++j)
          acc[i][j] = fmaf(a_[i], b_[j], acc[i][j]);
    }
    __syncthreads();
  }
#pragma unroll
  for (int i = 0; i < 4; ++i) {
    int r = rowBase + (ty << 2) + i;
    if (r >= M) continue;
#pragma unroll
    for (int j = 0; j < 4; ++j) {
      int c = colBase + (tx << 2) + j;
      out[(size_t)r * NB + c] = f2bf(acc[i][j] + bias[c]);
    }
  }
}

// ---------------- GEMM 2: h2 = relu( (y*A1+B1) @ W2 + b2 ), bf16 out ----------------
__global__ __launch_bounds__(256) void gemm_h1w2(
    const float* __restrict__ Y, const float* __restrict__ A1c, const float* __restrict__ B1c,
    const float* __restrict__ B, const float* __restrict__ bias,
    u16* __restrict__ out, int M, int K, int NB)
{
  __shared__ float As[16][64];
  __shared__ float Bs[16][64];
  const int tid = threadIdx.x;
  const int tx = tid & 15, ty = tid >> 4;
  const int rowBase = blockIdx.x * 64;
  const int colBase = blockIdx.y * 64;
  const int la_r = tid >> 2, la_k = (tid & 3) << 2;
  const int lb_k = tid >> 4, lb_c = (tid & 15) << 2;
  float acc[4][4] = {};
  for (int k0 = 0; k0 < K; k0 += 16) {
    int ar = rowBase + la_r;
    float4 av = make_float4(0.f, 0.f, 0.f, 0.f);
    if (ar < M) {
      float4 yv = *(const float4*)&Y[(size_t)ar * K + k0 + la_k];
      float4 aa = *(const float4*)&A1c[k0 + la_k];
      float4 bb = *(const float4*)&B1c[k0 + la_k];
      av.x = fmaf(yv.x, aa.x, bb.x);
      av.y = fmaf(yv.y, aa.y, bb.y);
      av.z = fmaf(yv.z, aa.z, bb.z);
      av.w = fmaf(yv.w, aa.w, bb.w);
    }
    As[la_k + 0][la_r] = av.x; As[la_k + 1][la_r] = av.y;
    As[la_k + 2][la_r] = av.z; As[la_k + 3][la_r] = av.w;
    *(float4*)&Bs[lb_k][lb_c] = *(const float4*)&B[(size_t)(k0 + lb_k) * NB + colBase + lb_c];
    __syncthreads();
#pragma unroll
    for (int k = 0; k < 16; ++k) {
      float a_[4], b_[4];
      *(float4*)a_ = *(const float4*)&As[k][ty << 2];
      *(float4*)b_ = *(const float4*)&Bs[k][tx << 2];
#pragma unroll
      for (int i = 0; i < 4; ++i)
#pragma unroll
        for (int j = 0; j < 4; ++j)
          acc[i][j] = fmaf(a_[i], b_[j], acc[i][j]);
    }
    __syncthreads();
  }
#pragma unroll
  for (int i = 0; i < 4; ++i) {
    int r = rowBase + (ty << 2) + i;
    if (r >= M) continue;
#pragma unroll
    for (int j = 0; j < 4; ++j) {
      int c = colBase + (tx << 2) + j;
      float v = acc[i][j] + bias[c];
      v = fmaxf(v, 0.f);
      out[(size_t)r * NB + c] = f2bf(v);
    }
  }
}

// ---------------- GEMM 3: z(f32) = h2(bf16)[M,K] @ W3 + b3, + LN stats ----------------
__global__ __launch_bounds__(256) void gemm_h2w3(
    const u16* __restrict__ A, const float* __restrict__ B,
    const float* __restrict__ bias, float* __restrict__ out,
    double* __restrict__ stats, int M, int K, int NB)
{
  __shared__ float As[16][64];
  __shared__ float Bs[16][64];
  const int tid = threadIdx.x;
  const int tx = tid & 15, ty = tid >> 4;
  const int rowBase = blockIdx.x * 64;
  const int colBase = blockIdx.y * 64;
  const int la_r = tid >> 2, la_k = (tid & 3) << 2;
  const int lb_k = tid >> 4, lb_c = (tid & 15) << 2;
  float acc[4][4] = {};
  for (int k0 = 0; k0 < K; k0 += 16) {
    int ar = rowBase + la_r;
    float a0 = 0.f, a1 = 0.f, a2 = 0.f, a3 = 0.f;
    if (ar < M) {
      ushort4 u = *(const ushort4*)&A[(size_t)ar * K + k0 + la_k];
      a0 = bf2f(u.x); a1 = bf2f(u.y); a2 = bf2f(u.z); a3 = bf2f(u.w);
    }
    As[la_k + 0][la_r] = a0; As[la_k + 1][la_r] = a1;
    As[la_k + 2][la_r] = a2; As[la_k + 3][la_r] = a3;
    *(float4*)&Bs[lb_k][lb_c] = *(const float4*)&B[(size_t)(k0 + lb_k) * NB + colBase + lb_c];
    __syncthreads();
#pragma unroll
    for (int k = 0; k < 16; ++k) {
      float a_[4], b_[4];
      *(float4*)a_ = *(const float4*)&As[k][ty << 2];
      *(float4*)b_ = *(const float4*)&Bs[k][tx << 2];
#pragma unroll
      for (int i = 0; i < 4; ++i)
#pragma unroll
        for (int j = 0; j < 4; ++j)
          acc[i][j] = fmaf(a_[i], b_[j], acc[i][j]);
    }
    __syncthreads();
  }
  float s1 = 0.f, s2 = 0.f;
#pragma unroll
  for (int i = 0; i < 4; ++i) {
    int r = rowBase + (ty << 2) + i;
    if (r >= M) continue;
#pragma unroll
    for (int j = 0; j < 4; ++j) {
      int c = colBase + (tx << 2) + j;
      float v = acc[i][j] + bias[c];
      out[(size_t)r * NB + c] = v;
      s1 += v;
      s2 += v * v;
    }
  }
  // wave-level reduction of LN stats
#pragma unroll
  for (int d = 1; d < 64; d <<= 1) {
    s1 += __shfl_xor(s1, d);
    s2 += __shfl_xor(s2, d);
  }
  if ((threadIdx.x & 63) == 0) {
    atomicAdd(&stats[0], (double)s1);
    atomicAdd(&stats[1], (double)s2);
  }
}

// ---------------- CSR build ----------------
__global__ void deg_count(const int* __restrict__ dst, int* __restrict__ deg, int E) {
  int i = blockIdx.x * blockDim.x + threadIdx.x;
  if (i < E) atomicAdd(&deg[dst[i]], 1);
}

__global__ __launch_bounds__(1024) void scan_k(const int* __restrict__ deg, int* __restrict__ off, int n) {
  __shared__ int wsum[16];
  __shared__ int carrySh;
  const int tid = threadIdx.x, lane = tid & 63, w = tid >> 6;
  if (tid == 0) carrySh = 0;
  __syncthreads();
  for (int base = 0; base < n; base += 1024) {
    int i = base + tid;
    int v = (i < n) ? deg[i] : 0;
    int incl = v;
#pragma unroll
    for (int d = 1; d < 64; d <<= 1) {
      int t = __shfl_up(incl, d);
      if (lane >= d) incl += t;
    }
    if (lane == 63) wsum[w] = incl;
    __syncthreads();
    int waveOff = 0, total = 0;
#pragma unroll
    for (int k = 0; k < 16; ++k) {
      int s = wsum[k];
      if (k < w) waveOff += s;
      total += s;
    }
    int carry = carrySh;
    if (i < n) off[i] = carry + waveOff + incl - v;
    __syncthreads();
    if (tid == 0) carrySh = carry + total;
    __syncthreads();
  }
  if (threadIdx.x == 0) off[n] = carrySh;
}

__global__ void fill_csr(const int* __restrict__ src, const int* __restrict__ dst,
                         const int* __restrict__ off, int* __restrict__ cur,
                         int* __restrict__ csr, int E) {
  int i = blockIdx.x * blockDim.x + threadIdx.x;
  if (i < E) {
    int d = dst[i];
    int pos = off[d] + atomicAdd(&cur[d], 1);
    csr[pos] = src[i];
  }
}

// ---------------- fused GATv2 edge-softmax-aggregate: one wave per node ----------------
__global__ __launch_bounds__(256) void gat_agg(
    const u16* __restrict__ xl, const u16* __restrict__ xr,
    const float* __restrict__ x, const int* __restrict__ off,
    const int* __restrict__ csr, const float* __restrict__ att,
    const float* __restrict__ b_gat, float* __restrict__ y,
    double* __restrict__ stats, int N)
{
  const int lane = threadIdx.x & 63;
  const int node = blockIdx.x * 4 + (threadIdx.x >> 6);
  if (node >= N) return;
  const int v0 = lane << 2;   // this lane's 4 feature slots; head = v0>>5 = lane>>3
  float attv[4];
  *(float4*)attv = *(const float4*)&att[v0];
  float xrv[4];
  {
    ushort4 u = *(const ushort4*)&xr[(size_t)node * HC + v0];
    xrv[0] = bf2f(u.x); xrv[1] = bf2f(u.y); xrv[2] = bf2f(u.z); xrv[3] = bf2f(u.w);
  }
  float m_run = -INFINITY, d_run = 0.f;
  float agg[4] = {0.f, 0.f, 0.f, 0.f};
  const int beg = off[node];
  const int cntE = off[node + 1] - beg;
  for (int e = -1; e < cntE; ++e) {       // e == -1 is the self-loop
    int j = (e < 0) ? node : csr[beg + e];
    ushort4 u = *(const ushort4*)&xl[(size_t)j * HC + v0];
    float xlv[4] = {bf2f(u.x), bf2f(u.y), bf2f(u.z), bf2f(u.w)};
    float part = 0.f;
#pragma unroll
    for (int m = 0; m < 4; ++m) {
      float s = xlv[m] + xrv[m];
      s = (s > 0.f) ? s : NEG * s;
      part = fmaf(attv[m], s, part);
    }
    // reduce over the 8 lanes sharing this head (all 8 end with the sum)
    part += __shfl_xor(part, 1);
    part += __shfl_xor(part, 2);
    part += __shfl_xor(part, 4);
    if (part > m_run) {
      float r = __expf(m_run - part);     // exp(-inf)=0 on first edge
      d_run = fmaf(d_run, r, 1.f);
#pragma unroll
      for (int m = 0; m < 4; ++m) agg[m] = fmaf(agg[m], r, xlv[m]);
      m_run = part;
    } else {
      float p = __expf(part - m_run);
      d_run += p;
#pragma unroll
      for (int m = 0; m < 4; ++m) agg[m] = fmaf(p, xlv[m], agg[m]);
    }
  }
  const float inv = 1.f / d_run;
  float xv[4], bg[4];
  *(float4*)xv = *(const float4*)&x[(size_t)node * HC + v0];
  *(float4*)bg = *(const float4*)&b_gat[v0];
  float outv[4];
  float s1 = 0.f, s2 = 0.f;
#pragma unroll
  for (int m = 0; m < 4; ++m) {
    float v = fmaf(agg[m], inv, bg[m]) + xv[m];  // y = x + gat_out
    outv[m] = v;
    s1 += v;
    s2 += v * v;
  }
  *(float4*)&y[(size_t)node * HC + v0] = *(float4*)outv;
#pragma unroll
  for (int d = 1; d < 64; d <<= 1) {
    s1 += __shfl_xor(s1, d);
    s2 += __shfl_xor(s2, d);
  }
  if (lane == 0) {
    atomicAdd(&stats[0], (double)s1);
    atomicAdd(&stats[1], (double)s2);
  }
}

// ---------------- LayerNorm finalize: fold (mu, std) into per-column affine ----------------
__global__ void ln_final(const double* __restrict__ S, const float* __restrict__ g,
                         const float* __restrict__ be, float* __restrict__ Aout,
                         float* __restrict__ Bout, double cnt) {
  double mu = S[0] / cnt;
  double var = S[1] / cnt - mu * mu;
  if (var < 0.0) var = 0.0;
  float sc = (float)(1.0 / (sqrt(var) + (double)LN_EPS));
  int c = threadIdx.x;
  float gg = g[c];
  Aout[c] = sc * gg;
  Bout[c] = be[c] - (float)mu * sc * gg;
}

// ---------------- apply LN3 in place on d_out ----------------
__global__ void ln_apply(float* __restrict__ z, const float* __restrict__ A3,
                         const float* __restrict__ B3, long total4) {
  for (long i = blockIdx.x * (long)blockDim.x + threadIdx.x; i < total4;
       i += (long)gridDim.x * blockDim.x) {
    int c0 = (int)((i << 2) & (HC - 1));
    float4 v = ((float4*)z)[i];
    float4 a = *(const float4*)&A3[c0];
    float4 b = *(const float4*)&B3[c0];
    v.x = fmaf(v.x, a.x, b.x);
    v.y = fmaf(v.y, a.y, b.y);
    v.z = fmaf(v.z, a.z, b.z);
    v.w = fmaf(v.w, a.w, b.w);
    ((float4*)z)[i] = v;
  }
}

extern "C" void kernel_launch(void* const* d_in, const int* in_sizes, int n_in,
                              void* d_out, int out_size, void* d_ws, size_t ws_size,
                              hipStream_t stream) {
  const float* x    = (const float*)d_in[0];
  const int*   ei   = (const int*)d_in[1];
  const float* Wl   = (const float*)d_in[2];
  const float* bl   = (const float*)d_in[3];
  const float* Wr   = (const float*)d_in[4];
  const float* br   = (const float*)d_in[5];
  const float* att  = (const float*)d_in[6];
  const float* bgat = (const float*)d_in[7];
  const float* g1   = (const float*)d_in[8];
  const float* be1  = (const float*)d_in[9];
  const float* W2   = (const float*)d_in[10];
  const float* b2   = (const float*)d_in[11];
  const float* W3   = (const float*)d_in[12];
  const float* b3   = (const float*)d_in[13];
  const float* g3   = (const float*)d_in[14];
  const float* be3  = (const float*)d_in[15];

  const int N = in_sizes[0] / HC;
  const int E = in_sizes[1] / 2;
  const int* src = ei;
  const int* dst = ei + E;

  char* ws = (char*)d_ws;
  size_t o = 0;
  double* stats = (double*)(ws + o); o += 64;              // 4 doubles (LN1: 0,1  LN3: 2,3)
  float* A1 = (float*)(ws + o); o += HC * 4;
  float* B1 = (float*)(ws + o); o += HC * 4;
  float* A3 = (float*)(ws + o); o += HC * 4;
  float* B3 = (float*)(ws + o); o += HC * 4;
  int* deg = (int*)(ws + o); o += (size_t)N * 4;
  int* cur = (int*)(ws + o); o += (size_t)N * 4;           // contiguous with deg (one memset)
  int* off = (int*)(ws + o); o += (size_t)(N + 1) * 4; o = (o + 15) & ~(size_t)15;
  int* csr = (int*)(ws + o); o += (size_t)E * 4; o = (o + 15) & ~(size_t)15;
  u16* xl = (u16*)(ws + o); o += (size_t)N * HC * 2;
  u16* xr = (u16*)(ws + o); o += (size_t)N * HC * 2;
  u16* h2 = (u16*)(ws + o); o += (size_t)N * DHID * 2;

  float* y = (float*)d_out;   // y (= x + gat_out) lives in d_out until GEMM2 consumes it
  float* z = (float*)d_out;   // then z (= h2@W3+b3) overwrites it; LN3 applied in place

  hipMemsetAsync(stats, 0, 64, stream);
  hipMemsetAsync(deg, 0, (size_t)N * 8, stream);           // deg + cur

  dim3 blk(256);
  const int mb = (N + 63) / 64;

  gemm_xw_bf16<<<dim3(mb, HC / 64), blk, 0, stream>>>(x, Wl, bl, xl, N, HC, HC);
  gemm_xw_bf16<<<dim3(mb, HC / 64), blk, 0, stream>>>(x, Wr, br, xr, N, HC, HC);

  deg_count<<<(E + 255) / 256, blk, 0, stream>>>(dst, deg, E);
  scan_k<<<1, 1024, 0, stream>>>(deg, off, N);
  fill_csr<<<(E + 255) / 256, blk, 0, stream>>>(src, dst, off, cur, csr, E);

  gat_agg<<<(N + 3) / 4, blk, 0, stream>>>(xl, xr, x, off, csr, att, bgat, y, stats, N);

  ln_final<<<1, HC, 0, stream>>>(stats, g1, be1, A1, B1, (double)N * HC);

  gemm_h1w2<<<dim3(mb, DHID / 64), blk, 0, stream>>>(y, A1, B1, W2, b2, h2, N, HC, DHID);

  gemm_h2w3<<<dim3(mb, HC / 64), blk, 0, stream>>>(h2, W3, b3, z, stats + 2, N, DHID, HC);

  ln_final<<<1, HC, 0, stream>>>(stats + 2, g3, be3, A3, B3, (double)N * HC);

  ln_apply<<<2048, blk, 0, stream>>>(z, A3, B3, (long)N * HC / 4);
}